// Round 1
// baseline (111670.532 us; speedup 1.0000x reference)
//
#include <hip/hip_runtime.h>
#include <hip/hip_bf16.h>

typedef unsigned short u16;
typedef __attribute__((ext_vector_type(8))) short short8;
typedef __attribute__((ext_vector_type(4))) float f32x4;

#define WSLOT   (1u<<20)            // 1 MiB per packed-weight slot (u16 count = 524288)
#define BIAS_OFF (5u<<20)
#define SEQ0_OFF (6u<<20)
#define SEQ_BYTES (67108864ull)     // 8gb*1024t*8kt*64lane*8j * 2B = 64 MiB

__device__ __forceinline__ u16 f2bf(float f){
    unsigned u = __float_as_uint(f);
    unsigned r = (u + 0x7FFFu + ((u>>16)&1u)) >> 16;   // RNE
    return (u16)r;
}
__device__ __forceinline__ float bf2f(u16 u){ return __uint_as_float(((unsigned)u)<<16); }

__device__ __forceinline__ float sigm(float x){ return __fdividef(1.f, 1.f + __expf(-x)); }
__device__ __forceinline__ float tanh_(float x){
    float e = __expf(-2.f*fabsf(x));
    float r = __fdividef(1.f - e, 1.f + e);
    return copysignf(r, x);
}

// ---- weight packing: rows permuted so each 16-col N-tile = 4 hidden units x (i,f,g,o),
// ---- stored in MFMA B-fragment slot order [ntg][kt][lane][j] (lane: col=l&15, k=8*(l>>4)+j)
__global__ void wprep(const float* __restrict__ Wih0, const float* __restrict__ Whh0,
                      const float* __restrict__ Wr,   const float* __restrict__ Whr,
                      u16* __restrict__ wp){
    int L = blockIdx.y;
    int KT = (L==0)?12:16;
    int KX = (L==0)?128:256;
    int total = 64*KT*512;
    int idx = blockIdx.x*256 + threadIdx.x;
    if (idx >= total) return;
    int j  = idx & 7;
    int l  = (idx>>3) & 63;
    int kt = (idx>>9) % KT;
    int ntg= (idx>>9) / KT;
    int p  = ntg*16 + (l&15);
    int w  = p>>7, nt = (p>>4)&7, c = p&15;
    int ul = 4*nt + (c>>2), g = c&3;
    int u  = 32*w + ul;
    int r  = g*256 + u;                  // original row in [4H]
    int k  = 32*kt + 8*(l>>4) + j;
    float v;
    if (L==0){
        v = (k < KX) ? Wih0[r*128 + k] : Whh0[r*256 + (k-KX)];
    } else {
        const float* wi = Wr  + (size_t)(L-1)*262144;
        const float* wh = Whr + (size_t)(L-1)*262144;
        v = (k < KX) ? wi[r*256 + k] : wh[r*256 + (k-KX)];
    }
    wp[(size_t)L*(WSLOT/2) + idx] = f2bf(v);
}

__global__ void bprep(const float* __restrict__ bih, const float* __restrict__ bhh,
                      float* __restrict__ bperm){
    int idx = blockIdx.x*256 + threadIdx.x;   // 5*1024
    if (idx >= 5120) return;
    int L = idx>>10, p = idx&1023;
    int w = p>>7, nt = (p>>4)&7, c = p&15;
    int ul = 4*nt + (c>>2), g = c&3;
    int r = g*256 + 32*w + ul;
    bperm[idx] = bih[L*1024 + r] + bhh[L*1024 + r];
}

// ---- fused per-layer kernel: gates = Wpacked @ [x_t ; h_{t-1}] + bias, 1024 steps.
// 8 WGs (one per 16-batch group), 512 threads = 8 waves; wave w owns gate cols [128w,128w+128).
template<int KTX, bool INPLACE, bool LAYER0>
__global__ __launch_bounds__(512, 2) void lstm_layer(
        const float* __restrict__ x,     // LAYER0 raw input [128][1024][128]
        const u16*   __restrict__ xin,   // L>0 frag input [gb][t][8][64][8]
        const u16*   __restrict__ wp,    // packed weights for this layer
        const float* __restrict__ bperm, // permuted bias [1024]
        u16*         __restrict__ hout)  // [gb][t][8][64][8]
{
    constexpr int KT = KTX + 8;
    const int gb  = blockIdx.x;
    const int tid = threadIdx.x;
    const int w   = tid>>6, l = tid&63;
    const int b15 = l&15,  q = l>>4;

    __shared__ __align__(16) u16 hbuf[2][8][64][8];     // 16 KiB, h fragments (double buffered)
    __shared__ _Float16 gbuf[8][16][132];               // 33 KiB, per-wave gate staging

    { // zero both h parities (h0 = 0)
        uint4* hb = (uint4*)hbuf;
        uint4 z = make_uint4(0u,0u,0u,0u);
        for (int i = tid; i < 1024; i += 512) hb[i] = z;
    }
    float c[8];
    #pragma unroll
    for (int i=0;i<8;++i) c[i] = 0.f;
    float biasr[8];
    #pragma unroll
    for (int nt=0;nt<8;++nt) biasr[nt] = bperm[128*w + 16*nt + b15];

    for (int t=0; t<1024; ++t){
        __syncthreads();                      // h frags (and t=0 zeros) visible
        short8 a[KT];
        if (LAYER0){
            #pragma unroll
            for (int kt=0; kt<KTX; ++kt){
                const float* xp = x + ((size_t)(gb*16 + b15)*1024 + t)*128 + 32*kt + 8*q;
                float4 f0 = *(const float4*)xp;
                float4 f1 = *(const float4*)(xp+4);
                short8 av;
                av[0]=(short)f2bf(f0.x); av[1]=(short)f2bf(f0.y);
                av[2]=(short)f2bf(f0.z); av[3]=(short)f2bf(f0.w);
                av[4]=(short)f2bf(f1.x); av[5]=(short)f2bf(f1.y);
                av[6]=(short)f2bf(f1.z); av[7]=(short)f2bf(f1.w);
                a[kt] = av;
            }
        } else {
            #pragma unroll
            for (int kt=0; kt<KTX; ++kt)
                a[kt] = *(const short8*)(xin + ((((size_t)gb*1024 + t)*8 + kt)*64 + l)*8);
        }
        #pragma unroll
        for (int kt=0; kt<8; ++kt)
            a[KTX+kt] = *(const short8*)&hbuf[t&1][kt][l][0];
        if (!LAYER0 && INPLACE) __syncthreads();   // drain input reads before we overwrite [t]

        #pragma unroll
        for (int np=0; np<4; ++np){
            const int n0 = 2*np, n1 = n0+1;
            const short8* B0 = (const short8*)wp + ((size_t)(8*w + n0)*KT)*64 + l;
            const short8* B1 = (const short8*)wp + ((size_t)(8*w + n1)*KT)*64 + l;
            float b0v = biasr[n0], b1v = biasr[n1];
            f32x4 acc0 = {b0v,b0v,b0v,b0v};
            f32x4 acc1 = {b1v,b1v,b1v,b1v};
            #pragma unroll
            for (int kt=0; kt<KT; ++kt){
                acc0 = __builtin_amdgcn_mfma_f32_16x16x32_bf16(a[kt], B0[kt*64], acc0, 0,0,0);
                acc1 = __builtin_amdgcn_mfma_f32_16x16x32_bf16(a[kt], B1[kt*64], acc1, 0,0,0);
            }
            #pragma unroll
            for (int r=0;r<4;++r){   // D: col=l&15, row=4*(l>>4)+r  [m89]
                gbuf[w][4*q + r][16*n0 + b15] = (_Float16)acc0[r];
                gbuf[w][4*q + r][16*n1 + b15] = (_Float16)acc1[r];
            }
        }
        __syncthreads();                      // cross-lane gate staging visible

        u16 hpack[8];
        #pragma unroll
        for (int i=0;i<8;++i){                // lane owns (b=b15, u_local=8q+i)
            const _Float16* gp = &gbuf[w][b15][32*q + 16*(i>>2) + 4*(i&3)];
            float ig = sigm((float)gp[0]);
            float fg = sigm((float)gp[1]);
            float gg = tanh_((float)gp[2]);
            float og = sigm((float)gp[3]);
            c[i] = fg*c[i] + ig*gg;
            hpack[i] = f2bf(og * tanh_(c[i]));
        }
        uint4 hv4;
        hv4.x = (unsigned)hpack[0] | ((unsigned)hpack[1]<<16);
        hv4.y = (unsigned)hpack[2] | ((unsigned)hpack[3]<<16);
        hv4.z = (unsigned)hpack[4] | ((unsigned)hpack[5]<<16);
        hv4.w = (unsigned)hpack[6] | ((unsigned)hpack[7]<<16);
        *(uint4*)&hbuf[(t+1)&1][w][l][0] = hv4;                       // next-step A frag
        *(uint4*)(hout + ((((size_t)gb*1024 + t)*8 + w)*64 + l)*8) = hv4;  // next-layer input
    }
}

__global__ void fc_kernel(const u16* __restrict__ hseq, const float* __restrict__ fcW,
                          const float* __restrict__ fcb, float* __restrict__ out){
    int n = blockIdx.x*256 + threadIdx.x;   // 131072 = [b][t]
    int b = n>>10, t = n&1023;
    int gb = b>>4, b16 = b&15;
    float acc = fcb[0];
    #pragma unroll
    for (int kt=0;kt<8;++kt){
        #pragma unroll
        for (int lg=0;lg<4;++lg){
            const u16* hp = hseq + ((((size_t)gb*1024 + t)*8 + kt)*64 + (b16 + 16*lg))*8;
            uint4 hv = *(const uint4*)hp;
            const float* wv = fcW + 32*kt + 8*lg;
            acc += bf2f((u16)(hv.x&0xffff))*wv[0] + bf2f((u16)(hv.x>>16))*wv[1]
                 + bf2f((u16)(hv.y&0xffff))*wv[2] + bf2f((u16)(hv.y>>16))*wv[3]
                 + bf2f((u16)(hv.z&0xffff))*wv[4] + bf2f((u16)(hv.z>>16))*wv[5]
                 + bf2f((u16)(hv.w&0xffff))*wv[6] + bf2f((u16)(hv.w>>16))*wv[7];
        }
    }
    out[n] = acc;
}

extern "C" void kernel_launch(void* const* d_in, const int* in_sizes, int n_in,
                              void* d_out, int out_size, void* d_ws, size_t ws_size,
                              hipStream_t stream){
    const float* x    = (const float*)d_in[0];
    const float* Wih0 = (const float*)d_in[1];
    const float* Whh0 = (const float*)d_in[2];
    const float* Wr   = (const float*)d_in[3];
    const float* Whr  = (const float*)d_in[4];
    const float* bih  = (const float*)d_in[5];
    const float* bhh  = (const float*)d_in[6];
    const float* fcW  = (const float*)d_in[7];
    const float* fcb  = (const float*)d_in[8];
    (void)in_sizes; (void)n_in; (void)out_size;

    char* ws   = (char*)d_ws;
    u16*  wp   = (u16*)ws;
    float* bpm = (float*)(ws + BIAS_OFF);
    u16*  seq0 = (u16*)(ws + SEQ0_OFF);
    bool  pp   = ws_size >= (size_t)SEQ0_OFF + 2*SEQ_BYTES;   // ping-pong if it fits
    u16*  seq1 = pp ? (u16*)(ws + SEQ0_OFF + SEQ_BYTES) : seq0;

    wprep<<<dim3(2048,5),256,0,stream>>>(Wih0, Whh0, Wr, Whr, wp);
    bprep<<<20,256,0,stream>>>(bih, bhh, bpm);

    // layer 0: raw x -> seq0
    lstm_layer<4,false,true><<<8,512,0,stream>>>(x, nullptr, wp, bpm, seq0);

    // layers 1..4
    u16* bufs[2] = {seq0, seq1};
    for (int L=1; L<5; ++L){
        u16* in  = bufs[(L-1)&1];
        u16* ob  = bufs[L&1];
        const u16* wL = wp + (size_t)L*(WSLOT/2);
        const float* bL = bpm + L*1024;
        if (pp) lstm_layer<8,false,false><<<8,512,0,stream>>>(nullptr, in, wL, bL, ob);
        else    lstm_layer<8,true ,false><<<8,512,0,stream>>>(nullptr, seq0, wL, bL, seq0);
    }
    // L4 output lands in bufs[0] = seq0 in both modes
    fc_kernel<<<512,256,0,stream>>>(seq0, fcW, fcb, (float*)d_out);
}

// Round 2
// 23473.845 us; speedup vs baseline: 4.7572x; 4.7572x over previous
//
#include <hip/hip_runtime.h>
#include <hip/hip_bf16.h>

typedef unsigned short u16;
typedef unsigned int u32;
typedef __attribute__((ext_vector_type(8))) short short8;
typedef __attribute__((ext_vector_type(4))) float f32x4;

#define WSLOT     (1u<<20)                    // 1 MiB per packed-weight slot
#define BIAS_OFF  (5u<<20)
#define WFLAG_OFF ((5u<<20) + (1u<<16))       // 5 layers * 8g * 1024t * 4B = 160KB
#define RFLAG_OFF (WFLAG_OFF + 163840u)       // another 160KB
#define SEQ0_OFF  (6u<<20)                    // 64 MiB seq buffer (A-frag layout)

__device__ __forceinline__ u16 f2bf(float f){
    unsigned u = __float_as_uint(f);
    unsigned r = (u + 0x7FFFu + ((u>>16)&1u)) >> 16;   // RNE
    return (u16)r;
}
__device__ __forceinline__ float bf2f(u16 u){ return __uint_as_float(((unsigned)u)<<16); }
__device__ __forceinline__ float sigm(float x){ return __fdividef(1.f, 1.f + __expf(-x)); }
__device__ __forceinline__ float tanh_(float x){
    float e = __expf(-2.f*fabsf(x));
    float r = __fdividef(1.f - e, 1.f + e);
    return copysignf(r, x);
}

#define MFMA16(a,b,c) __builtin_amdgcn_mfma_f32_16x16x32_bf16(a,b,c,0,0,0)

// ---- weight packing (unchanged from R1): rows permuted so each 16-col N-tile = 4 units x (i,f,g,o),
// ---- B-fragment slot order [ntg][kt][lane][j] (lane: col=l&15, k=8*(l>>4)+j)
__global__ void wprep(const float* __restrict__ Wih0, const float* __restrict__ Whh0,
                      const float* __restrict__ Wr,   const float* __restrict__ Whr,
                      u16* __restrict__ wp){
    int L = blockIdx.y;
    int KT = (L==0)?12:16;
    int KX = (L==0)?128:256;
    int total = 64*KT*512;
    int idx = blockIdx.x*256 + threadIdx.x;
    if (idx >= total) return;
    int j  = idx & 7;
    int l  = (idx>>3) & 63;
    int kt = (idx>>9) % KT;
    int ntg= (idx>>9) / KT;
    int p  = ntg*16 + (l&15);
    int w  = p>>7, nt = (p>>4)&7, c = p&15;
    int ul = 4*nt + (c>>2), g = c&3;
    int u  = 32*w + ul;
    int r  = g*256 + u;
    int k  = 32*kt + 8*(l>>4) + j;
    float v;
    if (L==0){
        v = (k < KX) ? Wih0[r*128 + k] : Whh0[r*256 + (k-KX)];
    } else {
        const float* wi = Wr  + (size_t)(L-1)*262144;
        const float* wh = Whr + (size_t)(L-1)*262144;
        v = (k < KX) ? wi[r*256 + k] : wh[r*256 + (k-KX)];
    }
    wp[(size_t)L*(WSLOT/2) + idx] = f2bf(v);
}

__global__ void bprep(const float* __restrict__ bih, const float* __restrict__ bhh,
                      float* __restrict__ bperm){
    int idx = blockIdx.x*256 + threadIdx.x;   // 5*1024
    if (idx >= 5120) return;
    int L = idx>>10, p = idx&1023;
    int w = p>>7, nt = (p>>4)&7, c = p&15;
    int ul = 4*nt + (c>>2), g = c&3;
    int r = g*256 + 32*w + ul;
    bperm[idx] = bih[L*1024 + r] + bhh[L*1024 + r];
}

__global__ void zflags(u32* __restrict__ f){
    f[blockIdx.x*256 + threadIdx.x] = 0u;     // 81920 u32 = both flag arrays
}

__device__ __forceinline__ void post_flag(u32* f){
    __hip_atomic_fetch_add(f, 1u, __ATOMIC_RELEASE, __HIP_MEMORY_SCOPE_AGENT);
}
__device__ __forceinline__ void wait_flag8(u32* f){
    while (__hip_atomic_load(f, __ATOMIC_ACQUIRE, __HIP_MEMORY_SCOPE_AGENT) < 8u)
        __builtin_amdgcn_s_sleep(1);
}

// ---- persistent-weight layer kernel. Grid = 64 WGs (cluster g = bid&7 on one XCD,
// ---- slice s = bid>>3 owns gate cols [128s,128s+128) = units [32s,32s+32)).
// ---- 256 threads = 4 waves; wave w owns n-tiles {8s+2w, 8s+2w+1}; B frags in VGPRs.
template<int KTX, bool LAYER0>
__global__ __launch_bounds__(256, 1) void lstm_p(
        const float* __restrict__ x,      // LAYER0 raw input [128][1024][128]
        const u16*   __restrict__ xin,    // L>0: seq buffer (also output -> in-place, rflag-guarded)
        const u16*   __restrict__ wp,     // this layer's packed weights
        const float* __restrict__ bperm,  // this layer's permuted bias [1024]
        u16*         __restrict__ seq,    // [g][t][kt][64][8]  (h exchange + next-layer input)
        u32*         __restrict__ wflag,  // [g][t] h-written counters (this layer's slice)
        u32*         __restrict__ rflag)  // [g][t] x-read counters
{
    constexpr int KT = KTX + 8;
    const int g = blockIdx.x & 7, s = blockIdx.x >> 3;
    const int tid = threadIdx.x;
    const int w = tid >> 6, l = tid & 63;
    const int b15 = l & 15, q = l >> 4;

    __shared__ __align__(16) float gbuf[16][132];
    __shared__ __align__(16) u16  hstage[16][32];

    // ---- persistent B fragments: 2 n-tiles x KT = 32 (24 for L0) short8 = 128 VGPRs
    short8 B0[KT], B1[KT];
    const int nt0 = 8*s + 2*w;
    #pragma unroll
    for (int kt=0; kt<KT; ++kt){
        B0[kt] = *(const short8*)(wp + (((size_t)(nt0  )*KT + kt)*64 + l)*8);
        B1[kt] = *(const short8*)(wp + (((size_t)(nt0+1)*KT + kt)*64 + l)*8);
    }
    const float bias0 = bperm[128*s + 32*w + b15];
    const float bias1 = bperm[128*s + 32*w + 16 + b15];

    const int ab = tid & 15, au = tid >> 4;   // activation ownership: (batch ab, units au, au+16)
    float c0 = 0.f, c1 = 0.f;

    u32* wf = wflag + g*1024;
    u32* rf = rflag + g*1024;

    for (int t=0; t<1024; ++t){
        // ---- x A-frags + x-part MFMAs (independent of peers)
        short8 a[KTX];
        if (LAYER0){
            const float* xp = x + ((size_t)(g*16 + b15)*1024 + t)*128 + 8*q;
            #pragma unroll
            for (int kt=0; kt<KTX; ++kt){
                float4 f0 = *(const float4*)(xp + 32*kt);
                float4 f1 = *(const float4*)(xp + 32*kt + 4);
                short8 av;
                av[0]=(short)f2bf(f0.x); av[1]=(short)f2bf(f0.y);
                av[2]=(short)f2bf(f0.z); av[3]=(short)f2bf(f0.w);
                av[4]=(short)f2bf(f1.x); av[5]=(short)f2bf(f1.y);
                av[6]=(short)f2bf(f1.z); av[7]=(short)f2bf(f1.w);
                a[kt] = av;
            }
        } else {
            const u16* xp = xin + (((size_t)g*1024 + t)*8)*512 + (size_t)l*8;
            #pragma unroll
            for (int kt=0; kt<KTX; ++kt)
                a[kt] = *(const short8*)(xp + kt*512);
        }
        f32x4 acc0 = {bias0,bias0,bias0,bias0};
        f32x4 acc1 = {bias1,bias1,bias1,bias1};
        #pragma unroll
        for (int kt=0; kt<KTX; ++kt){
            acc0 = MFMA16(a[kt], B0[kt], acc0);
            acc1 = MFMA16(a[kt], B1[kt], acc1);
        }
        __syncthreads();                         // all threads consumed x[t]
        if (tid == 0){
            if (!LAYER0) post_flag(rf + t);      // x[t] slot may now be overwritten by peers
            if (t > 0)   wait_flag8(wf + t - 1); // h[t-1] fully published
        }
        __syncthreads();

        // ---- h A-frags (device-coherent after acquire) + h-part MFMAs
        if (t > 0){
            const u16* hp = seq + (((size_t)g*1024 + (t-1))*8)*512 + (size_t)l*8;
            short8 ah[8];
            #pragma unroll
            for (int kt=0; kt<8; ++kt)
                ah[kt] = *(const short8*)(hp + kt*512);
            #pragma unroll
            for (int kt=0; kt<8; ++kt){
                acc0 = MFMA16(ah[kt], B0[KTX+kt], acc0);
                acc1 = MFMA16(ah[kt], B1[KTX+kt], acc1);
            }
        }
        // D layout: row(batch)=4q+r, col=l&15 within 16-tile [m89]
        #pragma unroll
        for (int r=0; r<4; ++r){
            gbuf[4*q + r][32*w + b15]      = acc0[r];
            gbuf[4*q + r][32*w + 16 + b15] = acc1[r];
        }
        __syncthreads();

        // ---- activation: thread owns (b=ab, slice-units au and au+16)
        {
            float4 gv0 = *(const float4*)&gbuf[ab][16*(au>>2) + 4*(au&3)];
            const int u1 = au + 16;
            float4 gv1 = *(const float4*)&gbuf[ab][16*(u1>>2) + 4*(u1&3)];
            float i0=sigm(gv0.x), ff0=sigm(gv0.y), gg0=tanh_(gv0.z), o0=sigm(gv0.w);
            c0 = ff0*c0 + i0*gg0;
            float h0 = o0*tanh_(c0);
            float i1=sigm(gv1.x), ff1=sigm(gv1.y), gg1=tanh_(gv1.z), o1=sigm(gv1.w);
            c1 = ff1*c1 + i1*gg1;
            float h1 = o1*tanh_(c1);
            hstage[ab][au]      = f2bf(h0);
            hstage[ab][au + 16] = f2bf(h1);
        }
        __syncthreads();

        // ---- publish h[t]: wave 0 writes the A-frag tile kt=s, then posts wflag
        if (w == 0){
            if (!LAYER0){ if (l == 0) wait_flag8(rf + t); }   // peers done reading x[t]
            // lanes reconverge here; store is program-ordered after the poll
            uint4 hv = *(const uint4*)&hstage[b15][8*q];
            *(uint4*)(seq + ((((size_t)g*1024 + t)*8 + s)*64 + l)*8) = hv;
            if (l == 0) post_flag(wf + t);       // release: vmcnt drain + L2 writeback
        }
    }
}

__global__ void fc_kernel(const u16* __restrict__ hseq, const float* __restrict__ fcW,
                          const float* __restrict__ fcb, float* __restrict__ out){
    int n = blockIdx.x*256 + threadIdx.x;   // 131072 = [b][t]
    int b = n>>10, t = n&1023;
    int gb = b>>4, b16 = b&15;
    float acc = fcb[0];
    #pragma unroll
    for (int kt=0;kt<8;++kt){
        #pragma unroll
        for (int lg=0;lg<4;++lg){
            const u16* hp = hseq + ((((size_t)gb*1024 + t)*8 + kt)*64 + (b16 + 16*lg))*8;
            uint4 hv = *(const uint4*)hp;
            const float* wv = fcW + 32*kt + 8*lg;
            acc += bf2f((u16)(hv.x&0xffff))*wv[0] + bf2f((u16)(hv.x>>16))*wv[1]
                 + bf2f((u16)(hv.y&0xffff))*wv[2] + bf2f((u16)(hv.y>>16))*wv[3]
                 + bf2f((u16)(hv.z&0xffff))*wv[4] + bf2f((u16)(hv.z>>16))*wv[5]
                 + bf2f((u16)(hv.w&0xffff))*wv[6] + bf2f((u16)(hv.w>>16))*wv[7];
        }
    }
    out[n] = acc;
}

extern "C" void kernel_launch(void* const* d_in, const int* in_sizes, int n_in,
                              void* d_out, int out_size, void* d_ws, size_t ws_size,
                              hipStream_t stream){
    const float* x    = (const float*)d_in[0];
    const float* Wih0 = (const float*)d_in[1];
    const float* Whh0 = (const float*)d_in[2];
    const float* Wr   = (const float*)d_in[3];
    const float* Whr  = (const float*)d_in[4];
    const float* bih  = (const float*)d_in[5];
    const float* bhh  = (const float*)d_in[6];
    const float* fcW  = (const float*)d_in[7];
    const float* fcb  = (const float*)d_in[8];
    (void)in_sizes; (void)n_in; (void)out_size; (void)ws_size;

    char* ws   = (char*)d_ws;
    u16*  wp   = (u16*)ws;
    float* bpm = (float*)(ws + BIAS_OFF);
    u32*  wfl  = (u32*)(ws + WFLAG_OFF);     // [5][8][1024]
    u32*  rfl  = (u32*)(ws + RFLAG_OFF);     // [5][8][1024]
    u16*  seq  = (u16*)(ws + SEQ0_OFF);      // single in-place seq buffer

    wprep<<<dim3(2048,5),256,0,stream>>>(Wih0, Whh0, Wr, Whr, wp);
    bprep<<<20,256,0,stream>>>(bih, bhh, bpm);
    zflags<<<320,256,0,stream>>>(wfl);       // zeroes wfl AND rfl (contiguous 320KB)

    // layer 0: raw x -> seq
    lstm_p<4,true><<<64,256,0,stream>>>(x, nullptr, wp, bpm, seq,
                                        wfl + 0*8192, rfl + 0*8192);
    // layers 1..4: in-place seq -> seq (rflag-guarded)
    for (int L=1; L<5; ++L){
        lstm_p<8,false><<<64,256,0,stream>>>(nullptr, seq, wp + (size_t)L*(WSLOT/2),
                                             bpm + L*1024, seq,
                                             wfl + L*8192, rfl + L*8192);
    }
    fc_kernel<<<512,256,0,stream>>>(seq, fcW, fcb, (float*)d_out);
}

// Round 6
// 5450.083 us; speedup vs baseline: 20.4897x; 4.3071x over previous
//
#include <hip/hip_runtime.h>
#include <hip/hip_bf16.h>

typedef unsigned short u16;
typedef unsigned int u32;
typedef __attribute__((ext_vector_type(8))) short short8;
typedef __attribute__((ext_vector_type(4))) float f32x4;
typedef unsigned int u32x4 __attribute__((ext_vector_type(4)));

// ---- workspace layout (70 MB total, same proven footprint as R1/R2)
#define WSLOT_U16 524288u                  // 1 MiB per packed-weight slot (u16 count)
#define BIAS_OFF  (5u<<20)                 // 20 KB
#define FLAG_OFF  ((5u<<20) + (1u<<15))    // wf[5][8][32] | rf[5][8][32] = 2560 u32
#define RING_OFF  ((5u<<20) + (1u<<16))    // ring[5][8][2][8][64][8] u16 = 640 KB
#define SEQ_OFF   (6u<<20)                 // final-layer output seq, 64 MB

__device__ __forceinline__ u16 f2bf(float f){
    unsigned u = __float_as_uint(f);
    return (u16)((u + 0x7FFFu + ((u>>16)&1u)) >> 16);   // RNE
}
__device__ __forceinline__ float bf2f(u16 u){ return __uint_as_float(((unsigned)u)<<16); }
__device__ __forceinline__ float sigm(float x){ return __fdividef(1.f, 1.f + __expf(-x)); }
__device__ __forceinline__ float tanh_(float x){
    float e = __expf(-2.f*fabsf(x));
    float r = __fdividef(1.f - e, 1.f + e);
    return copysignf(r, x);
}
#define MFMA16(a,b,c) __builtin_amdgcn_mfma_f32_16x16x32_bf16(a,b,c,0,0,0)

__device__ __forceinline__ void vm0(){ asm volatile("s_waitcnt vmcnt(0)" ::: "memory"); }

// ---- MALL-coherent exchange primitives (sc0 sc1: bypass L1+L2 both ways).
// Correct for ANY WG->XCD mapping; no cache-maintenance instructions ever.
__device__ __forceinline__ u32 pollw(const u32* p){
    u32 r;
    asm volatile("global_load_dword %0, %1, off sc0 sc1\n\ts_waitcnt vmcnt(0)"
                 : "=v"(r) : "v"(p) : "memory");
    return r;
}
__device__ __forceinline__ void postw(u32* p, u32 v){
    asm volatile("global_store_dword %0, %1, off sc0 sc1" :: "v"(p), "v"(v) : "memory");
}
// global_* imm offset is 13-bit SIGNED (<=4095): two base regs, offsets 0..3072.
__device__ __forceinline__ void ld8_sc(const u16* p, u32x4 d[8]){
    asm volatile(
        "global_load_dwordx4 %0, %8, off sc0 sc1\n\t"
        "global_load_dwordx4 %1, %8, off offset:1024 sc0 sc1\n\t"
        "global_load_dwordx4 %2, %8, off offset:2048 sc0 sc1\n\t"
        "global_load_dwordx4 %3, %8, off offset:3072 sc0 sc1\n\t"
        "global_load_dwordx4 %4, %9, off sc0 sc1\n\t"
        "global_load_dwordx4 %5, %9, off offset:1024 sc0 sc1\n\t"
        "global_load_dwordx4 %6, %9, off offset:2048 sc0 sc1\n\t"
        "global_load_dwordx4 %7, %9, off offset:3072 sc0 sc1\n\t"
        "s_waitcnt vmcnt(0)"
        : "=&v"(d[0]),"=&v"(d[1]),"=&v"(d[2]),"=&v"(d[3]),
          "=&v"(d[4]),"=&v"(d[5]),"=&v"(d[6]),"=&v"(d[7])
        : "v"(p), "v"(p + 2048) : "memory");
}
__device__ __forceinline__ void st16_sc(u16* p, u32x4 v){
    asm volatile("global_store_dwordx4 %0, %1, off sc0 sc1" :: "v"(p), "v"(v) : "memory");
}
// Bounded spin: a protocol bug becomes a fast diagnosable wrong answer, not a hang.
__device__ __forceinline__ void wait32(const u32* base, u32 v, int l, u32& budget){
    const u32* p = base + (l & 31);
    while (!__all((int)(pollw(p) >= v))){
        if (budget == 0u) return;
        --budget;
        __builtin_amdgcn_s_sleep(1);
    }
}

// ---- weight packing (validated R1/R2): each 16-col N-tile = 4 units x (i,f,g,o),
// ---- B-frag slot order [ntile][kt][lane][j], lane: col=l&15, k=8*(l>>4)+j
__global__ void wprep(const float* __restrict__ Wih0, const float* __restrict__ Whh0,
                      const float* __restrict__ Wr,   const float* __restrict__ Whr,
                      u16* __restrict__ wp){
    int L = blockIdx.y;
    int KT = (L==0)?12:16;
    int KX = (L==0)?128:256;
    int total = 64*KT*512;
    int idx = blockIdx.x*256 + threadIdx.x;
    if (idx >= total) return;
    int j  = idx & 7;
    int l  = (idx>>3) & 63;
    int kt = (idx>>9) % KT;
    int ntg= (idx>>9) / KT;
    int p  = ntg*16 + (l&15);
    int w  = p>>7, nt = (p>>4)&7, c = p&15;
    int ul = 4*nt + (c>>2), g = c&3;
    int r  = g*256 + 32*w + ul;
    int k  = 32*kt + 8*(l>>4) + j;
    float v;
    if (L==0){
        v = (k < KX) ? Wih0[r*128 + k] : Whh0[r*256 + (k-KX)];
    } else {
        const float* wi = Wr  + (size_t)(L-1)*262144;
        const float* wh = Whr + (size_t)(L-1)*262144;
        v = (k < KX) ? wi[r*256 + k] : wh[r*256 + (k-KX)];
    }
    wp[(size_t)L*WSLOT_U16 + idx] = f2bf(v);
}

__global__ void bprep(const float* __restrict__ bih, const float* __restrict__ bhh,
                      float* __restrict__ bperm){
    int idx = blockIdx.x*256 + threadIdx.x;   // 5*1024
    if (idx >= 5120) return;
    int L = idx>>10, p = idx&1023;
    int w = p>>7, nt = (p>>4)&7, c = p&15;
    int ul = 4*nt + (c>>2), g = c&3;
    int r = g*256 + 32*w + ul;
    bperm[idx] = bih[L*1024 + r] + bhh[L*1024 + r];
}

__global__ void zflags(u32* __restrict__ f){
    int i = blockIdx.x*256 + threadIdx.x;
    if (i < 2560) f[i] = 0u;
}

// ---- wavefront-pipelined 5-layer persistent LSTM.
// Grid 320 = 5 layers x (8 clusters x 8 slices). Cluster g owns batch rows [16g,16g+16);
// slice s owns units [32s,32s+32); wave w owns n-tiles {8s+2w, 8s+2w+1} (weights in VGPRs).
// Exchange via 2-slot rings at MALL (sc0 sc1), step-counter flag words, no barriers.
template<bool L0F>
__device__ void run_layer(const float* __restrict__ x, const u16* __restrict__ wp,
                          const float* __restrict__ bperm,
                          const u16* ring_in, u16* ring_self, u16* seqout,
                          u32* wf_prev, u32* wf_self, u32* rf_self, u32* rf_next,
                          int g, int s, int w, int l, float* gstrip)
{
    constexpr int KTX = L0F ? 4 : 8;
    constexpr int KT  = KTX + 8;
    const int b15 = l & 15, q = l >> 4;

    short8 B0[KT], B1[KT];     // persistent weights: 32 (24) short8 = 128 (96) VGPRs
    const int nt0 = 8*s + 2*w;
    #pragma unroll
    for (int kt=0; kt<KT; ++kt){
        B0[kt] = *(const short8*)(wp + (((size_t)(nt0  )*KT + kt)*64 + l)*8);
        B1[kt] = *(const short8*)(wp + (((size_t)(nt0+1)*KT + kt)*64 + l)*8);
    }
    const float bias0 = bperm[128*s + 32*w + b15];
    const float bias1 = bperm[128*s + 32*w + 16 + b15];

    const u32 widx = (u32)(s*4 + w);
    float cs0 = 0.f, cs1 = 0.f;
    u32 budget = (1u<<20);

    #pragma unroll 1
    for (int t=0; t<1024; ++t){
        // ---- x phase
        short8 ax[KTX];
        if constexpr (L0F){
            const float* xp = x + ((size_t)(g*16 + b15)*1024 + t)*128 + 8*q;
            #pragma unroll
            for (int kt=0; kt<KTX; ++kt){
                float4 f0 = *(const float4*)(xp + 32*kt);
                float4 f1 = *(const float4*)(xp + 32*kt + 4);
                short8 av;
                av[0]=(short)f2bf(f0.x); av[1]=(short)f2bf(f0.y);
                av[2]=(short)f2bf(f0.z); av[3]=(short)f2bf(f0.w);
                av[4]=(short)f2bf(f1.x); av[5]=(short)f2bf(f1.y);
                av[6]=(short)f2bf(f1.z); av[7]=(short)f2bf(f1.w);
                ax[kt] = av;
            }
        } else {
            wait32(wf_prev, (u32)(t+1), l, budget);       // input slot t published by layer L-1
            u32x4 d[8];
            ld8_sc(ring_in + (size_t)(t&1)*4096 + (size_t)l*8, d);
            #pragma unroll
            for (int kt=0; kt<8; ++kt) ax[kt] = __builtin_bit_cast(short8, d[kt]);
            if (l == 0) postw(rf_self + widx, (u32)(t+1)); // input slot t consumed
        }
        f32x4 acc0 = {bias0,bias0,bias0,bias0};
        f32x4 acc1 = {bias1,bias1,bias1,bias1};
        #pragma unroll
        for (int kt=0; kt<KTX; ++kt){
            acc0 = MFMA16(ax[kt], B0[kt], acc0);
            acc1 = MFMA16(ax[kt], B1[kt], acc1);
        }
        // ---- h phase
        if (t > 0){
            wait32(wf_self, (u32)t, l, budget);           // h[t-1] fully published by cluster
            u32x4 dh[8];
            ld8_sc(ring_self + (size_t)((t-1)&1)*4096 + (size_t)l*8, dh);
            #pragma unroll
            for (int kt=0; kt<8; ++kt){
                short8 ah = __builtin_bit_cast(short8, dh[kt]);
                acc0 = MFMA16(ah, B0[KTX+kt], acc0);
                acc1 = MFMA16(ah, B1[KTX+kt], acc1);
            }
        }
        // ---- D->gates transpose via per-wave LDS strip.
        // Stride 36 floats = 144 B: every f32x4 read is 16-B aligned (R5 bug: stride 34).
        #pragma unroll
        for (int r=0; r<4; ++r){
            gstrip[(4*q+r)*36 + b15]      = acc0[r];   // D: col=l&15, row=4*(l>>4)+r
            gstrip[(4*q+r)*36 + 16 + b15] = acc1[r];
        }
        f32x4 gv0 = *(const f32x4*)&gstrip[b15*36 + 8*q];       // unit 2q: i,f,g,o
        f32x4 gv1 = *(const f32x4*)&gstrip[b15*36 + 8*q + 4];   // unit 2q+1
        float i0=sigm(gv0[0]), ff0=sigm(gv0[1]), gg0=tanh_(gv0[2]), o0=sigm(gv0[3]);
        cs0 = ff0*cs0 + i0*gg0;
        float h0 = o0*tanh_(cs0);
        float i1=sigm(gv1[0]), ff1=sigm(gv1[1]), gg1=tanh_(gv1[2]), o1=sigm(gv1[3]);
        cs1 = ff1*cs1 + i1*gg1;
        float h1 = o1*tanh_(cs1);
        // ---- pack A-frag tile via 4x4 word transpose (3 shfl_xor)
        u32 word = (u32)f2bf(h0) | ((u32)f2bf(h1)<<16);
        u32 w1 = (u32)__shfl_xor((int)word, 16);
        u32 e0 = (q&1)? w1 : word, e1 = (q&1)? word : w1;
        u32 f0 = (u32)__shfl_xor((int)e0, 32);
        u32 f1 = (u32)__shfl_xor((int)e1, 32);
        u32x4 hv;
        hv[0] = (q<2)? e0:f0; hv[1] = (q<2)? e1:f1;
        hv[2] = (q<2)? f0:e0; hv[3] = (q<2)? f1:e1;
        // ---- publish h[t]: ring slot t&1 (overwrites step t-2; guard next layer's read)
        if (rf_next && t >= 2) wait32(rf_next, (u32)(t-1), l, budget);
        if (l < 16){
            st16_sc(ring_self + (size_t)(t&1)*4096 + s*512 + (size_t)(16*w + l)*8, hv);
            if (seqout)
                st16_sc(seqout + ((((size_t)g*1024 + t)*8 + s)*512) + (size_t)(16*w + l)*8, hv);
        }
        vm0();                                            // data acks from MALL before flag
        if (l == 0) postw(wf_self + widx, (u32)(t+1));
    }
}

__global__ __launch_bounds__(256,2) void lstm_all(
        const float* __restrict__ x, const u16* __restrict__ wp,
        const float* __restrict__ bpm, u16* ring, u16* seqout, u32* flags)
{
    __shared__ float gbuf[4][16][36];
    const int bid = blockIdx.x;
    const int L = bid >> 6, sub = bid & 63;
    const int g = sub & 7, s = sub >> 3;
    const int tid = threadIdx.x, w = tid >> 6, l = tid & 63;

    u32* wfb = flags;
    u32* rfb = flags + 1280;
    u32* wf_self = wfb + (L*8 + g)*32;
    u32* wf_prev = (L > 0) ? wfb + ((L-1)*8 + g)*32 : nullptr;
    u32* rf_self = (L > 0) ? rfb + (L*8 + g)*32 : nullptr;
    u32* rf_next = (L < 4) ? rfb + ((L+1)*8 + g)*32 : nullptr;
    u16* ring_self =     ring + (size_t)((L*8 + g)*2)*4096;
    const u16* ring_in = (L > 0) ? ring + (size_t)(((L-1)*8 + g)*2)*4096 : nullptr;
    const u16* wpL = wp + (size_t)L*WSLOT_U16;
    const float* bL = bpm + L*1024;
    u16* so = (L == 4) ? seqout : nullptr;

    if (L == 0)
        run_layer<true >(x, wpL, bL, ring_in, ring_self, so,
                         wf_prev, wf_self, rf_self, rf_next, g, s, w, l, &gbuf[w][0][0]);
    else
        run_layer<false>(x, wpL, bL, ring_in, ring_self, so,
                         wf_prev, wf_self, rf_self, rf_next, g, s, w, l, &gbuf[w][0][0]);
}

__global__ void fc_kernel(const u16* __restrict__ hseq, const float* __restrict__ fcW,
                          const float* __restrict__ fcb, float* __restrict__ out){
    int n = blockIdx.x*256 + threadIdx.x;   // 131072 = [b][t]
    int b = n>>10, t = n&1023;
    int gb = b>>4, b16 = b&15;
    float acc = fcb[0];
    #pragma unroll
    for (int kt=0;kt<8;++kt){
        #pragma unroll
        for (int lg=0;lg<4;++lg){
            const u16* hp = hseq + ((((size_t)gb*1024 + t)*8 + kt)*64 + (b16 + 16*lg))*8;
            uint4 hv = *(const uint4*)hp;
            const float* wv = fcW + 32*kt + 8*lg;
            acc += bf2f((u16)(hv.x&0xffff))*wv[0] + bf2f((u16)(hv.x>>16))*wv[1]
                 + bf2f((u16)(hv.y&0xffff))*wv[2] + bf2f((u16)(hv.y>>16))*wv[3]
                 + bf2f((u16)(hv.z&0xffff))*wv[4] + bf2f((u16)(hv.z>>16))*wv[5]
                 + bf2f((u16)(hv.w&0xffff))*wv[6] + bf2f((u16)(hv.w>>16))*wv[7];
        }
    }
    out[n] = acc;
}

extern "C" void kernel_launch(void* const* d_in, const int* in_sizes, int n_in,
                              void* d_out, int out_size, void* d_ws, size_t ws_size,
                              hipStream_t stream){
    const float* x    = (const float*)d_in[0];
    const float* Wih0 = (const float*)d_in[1];
    const float* Whh0 = (const float*)d_in[2];
    const float* Wr   = (const float*)d_in[3];
    const float* Whr  = (const float*)d_in[4];
    const float* bih  = (const float*)d_in[5];
    const float* bhh  = (const float*)d_in[6];
    const float* fcW  = (const float*)d_in[7];
    const float* fcb  = (const float*)d_in[8];
    (void)in_sizes; (void)n_in; (void)out_size; (void)ws_size;

    char* ws    = (char*)d_ws;
    u16*  wp    = (u16*)ws;
    float* bpm  = (float*)(ws + BIAS_OFF);
    u32*  flags = (u32*)(ws + FLAG_OFF);
    u16*  ring  = (u16*)(ws + RING_OFF);
    u16*  seq   = (u16*)(ws + SEQ_OFF);

    wprep<<<dim3(2048,5),256,0,stream>>>(Wih0, Whh0, Wr, Whr, wp);
    bprep<<<20,256,0,stream>>>(bih, bhh, bpm);
    zflags<<<10,256,0,stream>>>(flags);

    lstm_all<<<320,256,0,stream>>>(x, wp, bpm, ring, seq, flags);

    fc_kernel<<<512,256,0,stream>>>(seq, fcW, fcb, (float*)d_out);
}